// Round 1
// baseline (1576.537 us; speedup 1.0000x reference)
//
#include <hip/hip_runtime.h>

// ---------------------------------------------------------------------------
// MetaNet linearized model, MI355X.
// Key algebraic reductions:
//   f0 = mean_patches(xp) @ Wp + bp          (mean is linear -> only xbar needed)
//   df0 = (c0 (x) xbar) @ dWp_flat + sum_t c1 dbp[t]   (skinny GEMM, K=T*768)
//   dz  = df0 @ W1 + (c2 (x) f0) @ dW1_flat + sum_t c3 db1[t]
//   df  = (z>0) ? dz : 0
//   dout= df @ W2 + (c4 (x) f) @ dW2_flat + sum_t c5 db2[t]
//   out = base + dout,   base = relu(z) @ W2 + b2
// All intermediates stored transposed [N,32] so GEMM A-operand is wave-uniform
// -> compiler emits s_load (scalar cache), B streams coalesced from HBM.
// ---------------------------------------------------------------------------

__global__ void patch_partial_k(const float* __restrict__ x, float* __restrict__ part) {
    int blk = blockIdx.x;            // b*42 + ch*14 + i   (1344 blocks)
    int i  = blk % 14;
    int ch = (blk / 14) % 3;
    int b  = blk / 42;
    int t  = threadIdx.x;            // py*16 + px
    int py = t >> 4, px = t & 15;
    const float* xp = x + (((size_t)(b*3 + ch))*224 + (size_t)(i*16 + py))*224 + px;
    float s = 0.f;
#pragma unroll
    for (int j = 0; j < 14; ++j) s += xp[j*16];
    part[(size_t)blk*256 + t] = s;
}

__global__ void patch_reduce_k(const float* __restrict__ part, float* __restrict__ xbarT) {
    int idx = blockIdx.x*256 + threadIdx.x;   // 24576 = 32*768
    int b = idx / 768;
    int c = idx % 768;                        // c = ch*256 + py*16 + px
    int ch = c >> 8, t = c & 255;
    const float* p = part + ((size_t)(b*42 + ch*14))*256 + t;
    float s = 0.f;
#pragma unroll
    for (int i = 0; i < 14; ++i) s += p[i*256];
    xbarT[(size_t)c*32 + b] = s * (1.f/196.f);
}

// f0T/zT/baseT <- broadcast biases (accumulator init; GEMMs atomicAdd on top)
__global__ void init_bias3_k(float* __restrict__ f0T, const float* __restrict__ bp,
                             float* __restrict__ zT,  const float* __restrict__ b1,
                             float* __restrict__ baseT, const float* __restrict__ b2) {
    int idx = blockIdx.x*256 + threadIdx.x;   // 147456 = (768+3072+768)*32
    int b = idx & 31;
    int r = idx >> 5;
    if (r < 768)        f0T[idx] = bp[r];
    else if (r < 3840)  zT[(r-768)*32 + b]   = b1[r-768];
    else                baseT[(r-3840)*32 + b] = b2[r-3840];
}

// C_T[n][m] += sum_{k in tile} AT[k][m] * B[k][n]
// 64 threads/block, 1 column per thread, 32 fp32 accumulators.
// AT address is wave-uniform -> scalar loads. B load coalesced 256B/wave.
__global__ void gemm_skinny_k(const float* __restrict__ AT, const float* __restrict__ Bm,
                              float* __restrict__ CT, int N, int K, int kTile) {
    int col = blockIdx.x*64 + threadIdx.x;
    int k0 = blockIdx.y * kTile;
    int k1 = k0 + kTile; if (k1 > K) k1 = K;
    float acc[32];
#pragma unroll
    for (int m = 0; m < 32; ++m) acc[m] = 0.f;
    const float* bp = Bm + (size_t)k0*N + col;
    const float* ap = AT + (size_t)k0*32;
    for (int k = k0; k < k1; ++k) {
        float bv = *bp;
        bp += N;
#pragma unroll
        for (int m = 0; m < 32; ++m) acc[m] += ap[m] * bv;
        ap += 32;
    }
    float* cp = CT + (size_t)col*32;
#pragma unroll
    for (int m = 0; m < 32; ++m) atomicAdd(cp + m, acc[m]);
}

__global__ void relu_k(const float* __restrict__ zT, float* __restrict__ fT) {
    int idx = blockIdx.x*256 + threadIdx.x;   // 98304
    fT[idx] = fmaxf(zT[idx], 0.f);
}

__global__ void mask_k(const float* __restrict__ zT, const float* __restrict__ dzT,
                       float* __restrict__ dfT) {
    int idx = blockIdx.x*256 + threadIdx.x;   // 98304
    dfT[idx] = zT[idx] > 0.f ? dzT[idx] : 0.f;
}

// per-sample MetaNet: coefs[b,48] = relu(base[b]@mW1+mb1)@mW2+mb2
__global__ void metanet_k(const float* __restrict__ baseT, const float* __restrict__ mW1,
                          const float* __restrict__ mb1, const float* __restrict__ mW2,
                          const float* __restrict__ mb2, float* __restrict__ coefs) {
    int b = blockIdx.x;           // 32
    int j = threadIdx.x;          // 256
    __shared__ float v[192];
    if (j < 192) {
        float s = mb1[j];
        for (int i = 0; i < 768; ++i) s += baseT[i*32 + b] * mW1[i*192 + j];
        v[j] = fmaxf(s, 0.f);
    }
    __syncthreads();
    if (j < 48) {
        float s = mb2[j];
        for (int i = 0; i < 192; ++i) s += v[i] * mW2[i*48 + j];
        coefs[b*48 + j] = s;
    }
}

// Builds G0T/G1T/G2T (coef-scaled replicated A operands) and the three
// delta-bias accumulator inits, all in one launch.
__global__ void build_all_k(const float* __restrict__ coefs, const float* __restrict__ xbarT,
                            const float* __restrict__ f0T, const float* __restrict__ fT,
                            const float* __restrict__ dbp, const float* __restrict__ db1,
                            const float* __restrict__ db2,
                            float* __restrict__ G0T, float* __restrict__ G1T,
                            float* __restrict__ G2T, float* __restrict__ df0T,
                            float* __restrict__ dzT, float* __restrict__ doutT) {
    int idx = blockIdx.x*256 + threadIdx.x;   // 1327104 total
    int b = idx & 31;
    int r = idx >> 5;
    if (r < 6144) {                       // G0T[(t*768+i)*32+b] = c0 * xbar
        int t = r / 768, i = r % 768;
        G0T[idx] = coefs[b*48 + t*6 + 0] * xbarT[i*32 + b];
    } else if (r < 12288) {
        int rr = r - 6144;
        int t = rr / 768, i = rr % 768;
        G1T[rr*32 + b] = coefs[b*48 + t*6 + 2] * f0T[i*32 + b];
    } else if (r < 36864) {
        int rr = r - 12288;
        int t = rr / 3072, i = rr % 3072;
        G2T[rr*32 + b] = coefs[b*48 + t*6 + 4] * fT[i*32 + b];
    } else if (r < 37632) {
        int n = r - 36864;
        float s = 0.f;
#pragma unroll
        for (int t = 0; t < 8; ++t) s += coefs[b*48 + t*6 + 1] * dbp[t*768 + n];
        df0T[n*32 + b] = s;
    } else if (r < 40704) {
        int n = r - 37632;
        float s = 0.f;
#pragma unroll
        for (int t = 0; t < 8; ++t) s += coefs[b*48 + t*6 + 3] * db1[t*3072 + n];
        dzT[n*32 + b] = s;
    } else if (r < 41472) {
        int n = r - 40704;
        float s = 0.f;
#pragma unroll
        for (int t = 0; t < 8; ++t) s += coefs[b*48 + t*6 + 5] * db2[t*768 + n];
        doutT[n*32 + b] = s;
    }
}

__global__ void final_k(const float* __restrict__ baseT, const float* __restrict__ doutT,
                        float* __restrict__ out) {
    int idx = blockIdx.x*256 + threadIdx.x;   // 24576
    int b = idx / 768, n = idx % 768;
    out[idx] = baseT[n*32 + b] + doutT[n*32 + b];
}

extern "C" void kernel_launch(void* const* d_in, const int* in_sizes, int n_in,
                              void* d_out, int out_size, void* d_ws, size_t ws_size,
                              hipStream_t stream) {
    const float* x   = (const float*)d_in[0];
    const float* Wp  = (const float*)d_in[1];
    const float* bp  = (const float*)d_in[2];
    const float* W1  = (const float*)d_in[3];
    const float* b1  = (const float*)d_in[4];
    const float* W2  = (const float*)d_in[5];
    const float* b2  = (const float*)d_in[6];
    const float* dWp = (const float*)d_in[7];
    const float* dbp = (const float*)d_in[8];
    const float* dW1 = (const float*)d_in[9];
    const float* db1 = (const float*)d_in[10];
    const float* dW2 = (const float*)d_in[11];
    const float* db2 = (const float*)d_in[12];
    const float* mW1 = (const float*)d_in[13];
    const float* mb1 = (const float*)d_in[14];
    const float* mW2 = (const float*)d_in[15];
    const float* mb2 = (const float*)d_in[16];
    float* out = (float*)d_out;

    float* ws    = (float*)d_ws;
    float* part  = ws;                 // 344064
    float* xbarT = part  + 344064;     // 24576   [768,32]
    float* f0T   = xbarT + 24576;      // 24576   [768,32]
    float* zT    = f0T   + 24576;      // 98304   [3072,32]
    float* fT    = zT    + 98304;      // 98304   [3072,32]
    float* baseT = fT    + 98304;      // 24576   [768,32]
    float* coefs = baseT + 24576;      // 1536    [32,48]
    float* G0T   = coefs + 1536;       // 196608  [6144,32]
    float* G1T   = G0T   + 196608;     // 196608  [6144,32]
    float* G2T   = G1T   + 196608;     // 786432  [24576,32]
    float* df0T  = G2T   + 786432;     // 24576   [768,32]
    float* dzT   = df0T  + 24576;      // 98304   [3072,32]
    float* dfT   = dzT   + 98304;      // 98304   [3072,32]
    float* doutT = dfT   + 98304;      // 24576   [768,32]
    // total 2041344 floats = ~7.8 MB

    // 1) xbar = per-sample patch mean
    patch_partial_k<<<1344, 256, 0, stream>>>(x, part);
    patch_reduce_k<<<96, 256, 0, stream>>>(part, xbarT);

    // 2) base path: f0 -> z -> f -> base
    init_bias3_k<<<576, 256, 0, stream>>>(f0T, bp, zT, b1, baseT, b2);
    gemm_skinny_k<<<dim3(12, 8),  64, 0, stream>>>(xbarT, Wp, f0T, 768, 768, 96);
    gemm_skinny_k<<<dim3(48, 4),  64, 0, stream>>>(f0T, W1, zT, 3072, 768, 192);
    relu_k<<<384, 256, 0, stream>>>(zT, fT);
    gemm_skinny_k<<<dim3(12, 16), 64, 0, stream>>>(fT, W2, baseT, 768, 3072, 192);

    // 3) MetaNet coefficients
    metanet_k<<<32, 256, 0, stream>>>(baseT, mW1, mb1, mW2, mb2, coefs);

    // 4) scaled A-operands + delta-bias inits
    build_all_k<<<5184, 256, 0, stream>>>(coefs, xbarT, f0T, fT, dbp, db1, db2,
                                          G0T, G1T, G2T, df0T, dzT, doutT);

    // 5) JVP chain (the heavy streams: dWp 19MB, dW1 75MB, dW2 75MB)
    gemm_skinny_k<<<dim3(12, 24), 64, 0, stream>>>(G0T, dWp, df0T, 768, 6144, 256);
    gemm_skinny_k<<<dim3(48, 4),  64, 0, stream>>>(df0T, W1, dzT, 3072, 768, 192);
    gemm_skinny_k<<<dim3(48, 8),  64, 0, stream>>>(G1T, dW1, dzT, 3072, 6144, 768);
    mask_k<<<384, 256, 0, stream>>>(zT, dzT, dfT);
    gemm_skinny_k<<<dim3(12, 16), 64, 0, stream>>>(dfT, W2, doutT, 768, 3072, 192);
    gemm_skinny_k<<<dim3(12, 24), 64, 0, stream>>>(G2T, dW2, doutT, 768, 24576, 1024);

    // 6) out = base + dout  (transpose back to [B,768])
    final_k<<<96, 256, 0, stream>>>(baseT, doutT, out);
}

// Round 2
// 1467.467 us; speedup vs baseline: 1.0743x; 1.0743x over previous
//
#include <hip/hip_runtime.h>

// ---------------------------------------------------------------------------
// MetaNet linearized model, MI355X.
//   f0 = xbar @ Wp + bp                      (patch mean is linear)
//   df0 = (c0 (x) xbar) @ dWp_flat + sum_t c1 dbp[t]
//   z   = f0 @ W1 + b1 ; f = relu(z)
//   dz  = df0 @ W1 + (c2 (x) f0) @ dW1_flat + sum_t c3 db1[t]
//   base= f @ W2 + b2
//   dout= mask(dz) @ W2 + (c4 (x) f) @ dW2_flat + sum_t c5 db2[t]
//   out = base + dout
// Intermediates transposed [N,32]: GEMM A-operand wave-uniform -> s_load,
// B streamed coalesced. 16-deep load batching for MLP; k-split grids sized
// for 6-9 waves/CU; fp32 atomicAdd flush into bias-initialized accumulators.
// ---------------------------------------------------------------------------

__global__ void patch_partial_k(const float* __restrict__ x, float* __restrict__ part) {
    int blk = blockIdx.x;            // b*42 + ch*14 + i   (1344 blocks)
    int i  = blk % 14;
    int ch = (blk / 14) % 3;
    int b  = blk / 42;
    int t  = threadIdx.x;            // py*16 + px
    int py = t >> 4, px = t & 15;
    const float* xp = x + (((size_t)(b*3 + ch))*224 + (size_t)(i*16 + py))*224 + px;
    float s = 0.f;
#pragma unroll
    for (int j = 0; j < 14; ++j) s += xp[j*16];
    part[(size_t)blk*256 + t] = s;
}

__global__ void patch_reduce_k(const float* __restrict__ part, float* __restrict__ xbarT) {
    int idx = blockIdx.x*256 + threadIdx.x;   // 24576 = 32*768
    int b = idx / 768;
    int c = idx % 768;
    int ch = c >> 8, t = c & 255;
    const float* p = part + ((size_t)(b*42 + ch*14))*256 + t;
    float s = 0.f;
#pragma unroll
    for (int i = 0; i < 14; ++i) s += p[i*256];
    xbarT[(size_t)c*32 + b] = s * (1.f/196.f);
}

__global__ void init_bias3_k(float* __restrict__ f0T, const float* __restrict__ bp,
                             float* __restrict__ zT,  const float* __restrict__ b1,
                             float* __restrict__ baseT, const float* __restrict__ b2) {
    int idx = blockIdx.x*256 + threadIdx.x;   // 147456
    int b = idx & 31;
    int r = idx >> 5;
    if (r < 768)        f0T[idx] = bp[r];
    else if (r < 3840)  zT[(r-768)*32 + b]    = b1[r-768];
    else                baseT[(r-3840)*32 + b] = b2[r-3840];
}

// C_T[n][m] += sum_k A'[k][m] * B[k][n],  A' = A (MODE 0), relu(A) (MODE 1),
// (Z>0 ? A : 0) (MODE 2). One wave per block, 1 col/thread, 32 accumulators.
// 16 B-loads batched per chunk -> 4KB in flight per wave.
template<int N, int KTILE, int MODE>
__global__ __launch_bounds__(64) void gemm_k(const float* __restrict__ AT,
                                             const float* __restrict__ ZT,
                                             const float* __restrict__ Bm,
                                             float* __restrict__ CT) {
    int col = blockIdx.x*64 + threadIdx.x;
    size_t k0 = (size_t)blockIdx.y * KTILE;
    float acc[32];
#pragma unroll
    for (int m = 0; m < 32; ++m) acc[m] = 0.f;
    const float* bp = Bm + k0*N + col;
    const float* ap = AT + k0*32;
    const float* zp = ZT + k0*32;
    for (int kk = 0; kk < KTILE; kk += 16) {
        float bv[16];
#pragma unroll
        for (int u = 0; u < 16; ++u) bv[u] = bp[(size_t)u*N];
        bp += (size_t)16*N;
#pragma unroll
        for (int u = 0; u < 16; ++u) {
#pragma unroll
            for (int m = 0; m < 32; ++m) {
                float a = ap[u*32 + m];
                if (MODE == 1) a = fmaxf(a, 0.f);
                if (MODE == 2) a = (zp[u*32 + m] > 0.f) ? a : 0.f;
                acc[m] += a * bv[u];
            }
        }
        ap += 16*32;
        if (MODE == 2) zp += 16*32;
    }
    float* cp = CT + (size_t)col*32;
#pragma unroll
    for (int m = 0; m < 32; ++m) atomicAdd(cp + m, acc[m]);
}

// per-sample MetaNet: coefs[b,48] = relu(base[b]@mW1+mb1)@mW2+mb2
__global__ void metanet_k(const float* __restrict__ baseT, const float* __restrict__ mW1,
                          const float* __restrict__ mb1, const float* __restrict__ mW2,
                          const float* __restrict__ mb2, float* __restrict__ coefs) {
    int b = blockIdx.x;           // 32
    int j = threadIdx.x;          // 256
    __shared__ float xb[768];
    __shared__ float v[192];
    for (int i = j; i < 768; i += 256) xb[i] = baseT[(size_t)i*32 + b];
    __syncthreads();
    if (j < 192) {
        float s = mb1[j];
#pragma unroll 8
        for (int i = 0; i < 768; ++i) s += xb[i] * mW1[i*192 + j];
        v[j] = fmaxf(s, 0.f);
    }
    __syncthreads();
    if (j < 48) {
        float s = mb2[j];
#pragma unroll 8
        for (int i = 0; i < 192; ++i) s += v[i] * mW2[i*48 + j];
        coefs[b*48 + j] = s;
    }
}

// G0T/G1T/G2T (coef-scaled A operands) + delta-bias accumulator inits.
__global__ void build_all_k(const float* __restrict__ coefs, const float* __restrict__ xbarT,
                            const float* __restrict__ f0T, const float* __restrict__ zT,
                            const float* __restrict__ dbp, const float* __restrict__ db1,
                            const float* __restrict__ db2,
                            float* __restrict__ G0T, float* __restrict__ G1T,
                            float* __restrict__ G2T, float* __restrict__ df0T,
                            float* __restrict__ dzT, float* __restrict__ doutT) {
    int idx = blockIdx.x*256 + threadIdx.x;   // 1327104 total
    int b = idx & 31;
    int r = idx >> 5;
    if (r < 6144) {
        int t = r / 768, i = r % 768;
        G0T[idx] = coefs[b*48 + t*6 + 0] * xbarT[(size_t)i*32 + b];
    } else if (r < 12288) {
        int rr = r - 6144;
        int t = rr / 768, i = rr % 768;
        G1T[(size_t)rr*32 + b] = coefs[b*48 + t*6 + 2] * f0T[(size_t)i*32 + b];
    } else if (r < 36864) {
        int rr = r - 12288;
        int t = rr / 3072, i = rr % 3072;
        G2T[(size_t)rr*32 + b] = coefs[b*48 + t*6 + 4] * fmaxf(zT[(size_t)i*32 + b], 0.f);
    } else if (r < 37632) {
        int n = r - 36864;
        float s = 0.f;
#pragma unroll
        for (int t = 0; t < 8; ++t) s += coefs[b*48 + t*6 + 1] * dbp[t*768 + n];
        df0T[(size_t)n*32 + b] = s;
    } else if (r < 40704) {
        int n = r - 37632;
        float s = 0.f;
#pragma unroll
        for (int t = 0; t < 8; ++t) s += coefs[b*48 + t*6 + 3] * db1[t*3072 + n];
        dzT[(size_t)n*32 + b] = s;
    } else if (r < 41472) {
        int n = r - 40704;
        float s = 0.f;
#pragma unroll
        for (int t = 0; t < 8; ++t) s += coefs[b*48 + t*6 + 5] * db2[t*768 + n];
        doutT[(size_t)n*32 + b] = s;
    }
}

__global__ void final_k(const float* __restrict__ baseT, const float* __restrict__ doutT,
                        float* __restrict__ out) {
    int idx = blockIdx.x*256 + threadIdx.x;   // 24576
    int b = idx / 768, n = idx % 768;
    out[idx] = baseT[(size_t)n*32 + b] + doutT[(size_t)n*32 + b];
}

extern "C" void kernel_launch(void* const* d_in, const int* in_sizes, int n_in,
                              void* d_out, int out_size, void* d_ws, size_t ws_size,
                              hipStream_t stream) {
    const float* x   = (const float*)d_in[0];
    const float* Wp  = (const float*)d_in[1];
    const float* bp  = (const float*)d_in[2];
    const float* W1  = (const float*)d_in[3];
    const float* b1  = (const float*)d_in[4];
    const float* W2  = (const float*)d_in[5];
    const float* b2  = (const float*)d_in[6];
    const float* dWp = (const float*)d_in[7];
    const float* dbp = (const float*)d_in[8];
    const float* dW1 = (const float*)d_in[9];
    const float* db1 = (const float*)d_in[10];
    const float* dW2 = (const float*)d_in[11];
    const float* db2 = (const float*)d_in[12];
    const float* mW1 = (const float*)d_in[13];
    const float* mb1 = (const float*)d_in[14];
    const float* mW2 = (const float*)d_in[15];
    const float* mb2 = (const float*)d_in[16];
    float* out = (float*)d_out;

    float* ws    = (float*)d_ws;
    float* part  = ws;                 // 344064
    float* xbarT = part  + 344064;     // 24576   [768,32]
    float* f0T   = xbarT + 24576;      // 24576   [768,32]
    float* zT    = f0T   + 24576;      // 98304   [3072,32]
    float* baseT = zT    + 98304;      // 24576   [768,32]
    float* coefs = baseT + 24576;      // 1536    [32,48]
    float* G0T   = coefs + 1536;       // 196608  [6144,32]
    float* G1T   = G0T   + 196608;     // 196608  [6144,32]
    float* G2T   = G1T   + 196608;     // 786432  [24576,32]
    float* df0T  = G2T   + 786432;     // 24576   [768,32]
    float* dzT   = df0T  + 24576;      // 98304   [3072,32]
    float* doutT = dzT   + 98304;      // 24576   [768,32]

    // 1) per-sample patch mean
    patch_partial_k<<<1344, 256, 0, stream>>>(x, part);
    patch_reduce_k<<<96, 256, 0, stream>>>(part, xbarT);

    // 2) bias-init accumulators
    init_bias3_k<<<576, 256, 0, stream>>>(f0T, bp, zT, b1, baseT, b2);

    // 3) base path
    gemm_k<768, 32, 0><<<dim3(12, 24), 64, 0, stream>>>(xbarT, nullptr, Wp, f0T);   // f0
    gemm_k<3072, 48, 0><<<dim3(48, 16), 64, 0, stream>>>(f0T, nullptr, W1, zT);     // z
    gemm_k<768, 64, 1><<<dim3(12, 48), 64, 0, stream>>>(zT, nullptr, W2, baseT);    // base = relu(z)@W2

    // 4) MetaNet coefficients
    metanet_k<<<32, 256, 0, stream>>>(baseT, mW1, mb1, mW2, mb2, coefs);

    // 5) scaled A-operands + delta-bias inits
    build_all_k<<<5184, 256, 0, stream>>>(coefs, xbarT, f0T, zT, dbp, db1, db2,
                                          G0T, G1T, G2T, df0T, dzT, doutT);

    // 6) JVP chain (heavy streams: dWp 19MB, dW1 75MB, dW2 75MB)
    gemm_k<768, 64, 0><<<dim3(12, 96), 64, 0, stream>>>(G0T, nullptr, dWp, df0T);
    gemm_k<3072, 48, 0><<<dim3(48, 16), 64, 0, stream>>>(df0T, nullptr, W1, dzT);
    gemm_k<3072, 128, 0><<<dim3(48, 48), 64, 0, stream>>>(G1T, nullptr, dW1, dzT);
    gemm_k<768, 64, 2><<<dim3(12, 48), 64, 0, stream>>>(dzT, zT, W2, doutT);        // mask fused
    gemm_k<768, 128, 0><<<dim3(12, 192), 64, 0, stream>>>(G2T, nullptr, dW2, doutT);

    // 7) out = base + dout
    final_k<<<96, 256, 0, stream>>>(baseT, doutT, out);
}

// Round 4
// 558.297 us; speedup vs baseline: 2.8238x; 2.6285x over previous
//
#include <hip/hip_runtime.h>

// ---------------------------------------------------------------------------
// MetaNet linearized model, MI355X.
//   f0 = xbar @ Wp + bp                      (patch mean is linear)
//   z = f0@W1 + b1 ; f = relu(z) ; base = f@W2 + b2
//   df0 = (c0 (x) xbar)@dWp + sum_t c1 dbp
//   dz  = df0@W1 + (c2 (x) f0)@dW1 + sum_t c3 db1 ; df = mask(z) dz
//   dout= df@W2 + (c4 (x) f)@dW2 + sum_t c5 db2 ; out = base + dout
// GEMMs: A-operand [K,32] wave-uniform (s_load), B streamed coalesced with
// 16-deep load batching, k-split partial buffers (NO atomics), fused reduces.
// ---------------------------------------------------------------------------

__global__ void patch_partial_k(const float* __restrict__ x, float* __restrict__ part) {
    int blk = blockIdx.x;            // b*42 + ch*14 + i   (1344 blocks)
    int i  = blk % 14;
    int ch = (blk / 14) % 3;
    int b  = blk / 42;
    int t  = threadIdx.x;            // py*16 + px
    int py = t >> 4, px = t & 15;
    const float* xp = x + (((size_t)(b*3 + ch))*224 + (size_t)(i*16 + py))*224 + px;
    float s = 0.f;
#pragma unroll
    for (int j = 0; j < 14; ++j) s += xp[j*16];
    part[(size_t)blk*256 + t] = s;
}

__global__ void patch_reduce_k(const float* __restrict__ part, float* __restrict__ xbarT) {
    int idx = blockIdx.x*256 + threadIdx.x;   // 24576 = 32*768
    int b = idx / 768;
    int c = idx % 768;
    int ch = c >> 8, t = c & 255;
    const float* p = part + ((size_t)(b*42 + ch*14))*256 + t;
    float s = 0.f;
#pragma unroll
    for (int i = 0; i < 14; ++i) s += p[i*256];
    xbarT[(size_t)c*32 + b] = s * (1.f/196.f);
}

// P[y][col*32+m] = sum_{k in tile y} AT[k][m] * B[k][col]
// 1 wave/block, 1 col/thread, 32 accumulators, 16 B-loads batched (4KB/wave
// in flight). Plain stores into per-y-slice partial buffer — no atomics.
template<int N, int KTILE>
__global__ __launch_bounds__(64, 4) void gemm_k(const float* __restrict__ AT,
                                                const float* __restrict__ Bm,
                                                float* __restrict__ P) {
    int col = blockIdx.x*64 + threadIdx.x;
    size_t k0 = (size_t)blockIdx.y * KTILE;
    float acc[32];
#pragma unroll
    for (int m = 0; m < 32; ++m) acc[m] = 0.f;
    const float* bp = Bm + k0*N + col;
    const float* ap = AT + k0*32;
#pragma unroll 1
    for (int kk = 0; kk < KTILE; kk += 16) {
        float bv[16];
#pragma unroll
        for (int u = 0; u < 16; ++u) bv[u] = bp[(size_t)u*N];
        bp += (size_t)16*N;
#pragma unroll
        for (int u = 0; u < 16; ++u) {
#pragma unroll
            for (int m = 0; m < 32; ++m) acc[m] += ap[u*32 + m] * bv[u];
        }
        ap += 16*32;
    }
    float* p0 = P + (size_t)blockIdx.y*((size_t)N*32) + (size_t)col*32;
#pragma unroll
    for (int m = 0; m < 32; m += 4)
        *(float4*)(p0 + m) = make_float4(acc[m], acc[m+1], acc[m+2], acc[m+3]);
}

// out[idx] = bias[idx>>5] + sum_y P[y][idx]
template<int Y>
__global__ void reduce_bias_k(const float* __restrict__ P, const float* __restrict__ bias,
                              float* __restrict__ out, int SZ) {
    int idx = blockIdx.x*256 + threadIdx.x;
    float s = bias[idx >> 5];
#pragma unroll
    for (int y = 0; y < Y; ++y) s += P[(size_t)y*SZ + idx];
    out[idx] = s;
}

// z and f=relu(z) in one pass (SZ=98304)
template<int Y>
__global__ void reduce_zf_k(const float* __restrict__ P, const float* __restrict__ bias,
                            float* __restrict__ zT, float* __restrict__ fT) {
    int idx = blockIdx.x*256 + threadIdx.x;
    float s = bias[idx >> 5];
#pragma unroll
    for (int y = 0; y < Y; ++y) s += P[(size_t)y*98304 + idx];
    zT[idx] = s;
    fT[idx] = fmaxf(s, 0.f);
}

// out = init + sum_y P
template<int Y>
__global__ void reduce_arr_k(const float* __restrict__ P, const float* __restrict__ init,
                             float* __restrict__ out, int SZ) {
    int idx = blockIdx.x*256 + threadIdx.x;
    float s = init[idx];
#pragma unroll
    for (int y = 0; y < Y; ++y) s += P[(size_t)y*SZ + idx];
    out[idx] = s;
}

// dfT = (z>0) ? (init + sum_y P) : 0     (SZ=98304)
template<int Y>
__global__ void reduce_mask_k(const float* __restrict__ P, const float* __restrict__ init,
                              const float* __restrict__ zT, float* __restrict__ dfT) {
    int idx = blockIdx.x*256 + threadIdx.x;
    float s = init[idx];
#pragma unroll 16
    for (int y = 0; y < Y; ++y) s += P[(size_t)y*98304 + idx];
    dfT[idx] = zT[idx] > 0.f ? s : 0.f;
}

// out[b,n] = base + init + sum_y P   (un-transpose on store)
template<int Y>
__global__ void reduce_out_k(const float* __restrict__ P, const float* __restrict__ init,
                             const float* __restrict__ baseT, float* __restrict__ out) {
    int idx = blockIdx.x*256 + threadIdx.x;   // 24576
    float s = init[idx] + baseT[idx];
#pragma unroll 16
    for (int y = 0; y < Y; ++y) s += P[(size_t)y*24576 + idx];
    int n = idx >> 5, b = idx & 31;
    out[b*768 + n] = s;
}

// per-sample MetaNet: coefs[b,48] = relu(base[b]@mW1+mb1)@mW2+mb2
__global__ void metanet_k(const float* __restrict__ baseT, const float* __restrict__ mW1,
                          const float* __restrict__ mb1, const float* __restrict__ mW2,
                          const float* __restrict__ mb2, float* __restrict__ coefs) {
    int b = blockIdx.x;           // 32
    int j = threadIdx.x;          // 256
    __shared__ float xb[768];
    __shared__ float v[192];
    for (int i = j; i < 768; i += 256) xb[i] = baseT[(size_t)i*32 + b];
    __syncthreads();
    if (j < 192) {
        float s = mb1[j];
#pragma unroll 8
        for (int i = 0; i < 768; ++i) s += xb[i] * mW1[i*192 + j];
        v[j] = fmaxf(s, 0.f);
    }
    __syncthreads();
    if (j < 48) {
        float s = mb2[j];
#pragma unroll 8
        for (int i = 0; i < 192; ++i) s += v[i] * mW2[i*48 + j];
        coefs[b*48 + j] = s;
    }
}

// G0T/G1T/G2T (coef-scaled A operands) + delta-bias accumulator inits.
__global__ void build_all_k(const float* __restrict__ coefs, const float* __restrict__ xbarT,
                            const float* __restrict__ f0T, const float* __restrict__ fT,
                            const float* __restrict__ dbp, const float* __restrict__ db1,
                            const float* __restrict__ db2,
                            float* __restrict__ G0T, float* __restrict__ G1T,
                            float* __restrict__ G2T, float* __restrict__ df0b,
                            float* __restrict__ dzb, float* __restrict__ doutb) {
    int idx = blockIdx.x*256 + threadIdx.x;   // 1327104 total
    int b = idx & 31;
    int r = idx >> 5;
    if (r < 6144) {
        int t = r / 768, i = r % 768;
        G0T[idx] = coefs[b*48 + t*6 + 0] * xbarT[(size_t)i*32 + b];
    } else if (r < 12288) {
        int rr = r - 6144;
        int t = rr / 768, i = rr % 768;
        G1T[(size_t)rr*32 + b] = coefs[b*48 + t*6 + 2] * f0T[(size_t)i*32 + b];
    } else if (r < 36864) {
        int rr = r - 12288;
        int t = rr / 3072, i = rr % 3072;
        G2T[(size_t)rr*32 + b] = coefs[b*48 + t*6 + 4] * fT[(size_t)i*32 + b];
    } else if (r < 37632) {
        int n = r - 36864;
        float s = 0.f;
#pragma unroll
        for (int t = 0; t < 8; ++t) s += coefs[b*48 + t*6 + 1] * dbp[t*768 + n];
        df0b[(size_t)n*32 + b] = s;
    } else if (r < 40704) {
        int n = r - 37632;
        float s = 0.f;
#pragma unroll
        for (int t = 0; t < 8; ++t) s += coefs[b*48 + t*6 + 3] * db1[t*3072 + n];
        dzb[(size_t)n*32 + b] = s;
    } else if (r < 41472) {
        int n = r - 40704;
        float s = 0.f;
#pragma unroll
        for (int t = 0; t < 8; ++t) s += coefs[b*48 + t*6 + 5] * db2[t*768 + n];
        doutb[(size_t)n*32 + b] = s;
    }
}

extern "C" void kernel_launch(void* const* d_in, const int* in_sizes, int n_in,
                              void* d_out, int out_size, void* d_ws, size_t ws_size,
                              hipStream_t stream) {
    const float* x   = (const float*)d_in[0];
    const float* Wp  = (const float*)d_in[1];
    const float* bp  = (const float*)d_in[2];
    const float* W1  = (const float*)d_in[3];
    const float* b1  = (const float*)d_in[4];
    const float* W2  = (const float*)d_in[5];
    const float* b2  = (const float*)d_in[6];
    const float* dWp = (const float*)d_in[7];
    const float* dbp = (const float*)d_in[8];
    const float* dW1 = (const float*)d_in[9];
    const float* db1 = (const float*)d_in[10];
    const float* dW2 = (const float*)d_in[11];
    const float* db2 = (const float*)d_in[12];
    const float* mW1 = (const float*)d_in[13];
    const float* mb1 = (const float*)d_in[14];
    const float* mW2 = (const float*)d_in[15];
    const float* mb2 = (const float*)d_in[16];
    float* out = (float*)d_out;

    float* ws    = (float*)d_ws;
    float* part  = ws;                 // 344064
    float* xbarT = part  + 344064;     // 24576   [768,32]
    float* f0T   = xbarT + 24576;      // 24576
    float* zT    = f0T   + 24576;      // 98304
    float* fT    = zT    + 98304;      // 98304
    float* baseT = fT    + 98304;      // 24576
    float* coefs = baseT + 24576;      // 1536
    float* G0T   = coefs + 1536;       // 196608  [6144,32]
    float* G1T   = G0T   + 196608;     // 196608  [6144,32]
    float* G2T   = G1T   + 196608;     // 786432  [24576,32]
    float* df0b  = G2T   + 786432;     // 24576
    float* dzb   = df0b  + 24576;      // 98304
    float* doutb = dzb   + 98304;      // 24576
    float* dfT   = doutb + 24576;      // 98304
    float* df0T  = dfT   + 98304;      // 24576
    // partial arenas (reused across phases; no lifetime overlap)
    float* A1 = df0T + 24576;          // 3145728  : Pz (8),  then Pdz (32 slices of 98304)
    float* A2 = A1 + 3145728;          // 3145728  : Pbase(32), then Pdout (128 slices of 24576)
    float* A3 = A2 + 3145728;          // 1179648  : Pf0 (8), then Pdf0 (48 slices of 24576)
    // total ~9.6M floats = ~38.5 MB

    // 1) per-sample patch mean
    patch_partial_k<<<1344, 256, 0, stream>>>(x, part);
    patch_reduce_k<<<96, 256, 0, stream>>>(part, xbarT);

    // 2) base path
    gemm_k<768, 96><<<dim3(12, 8), 64, 0, stream>>>(xbarT, Wp, A3);
    reduce_bias_k<8><<<96, 256, 0, stream>>>(A3, bp, f0T, 24576);
    gemm_k<3072, 96><<<dim3(48, 8), 64, 0, stream>>>(f0T, W1, A1);
    reduce_zf_k<8><<<384, 256, 0, stream>>>(A1, b1, zT, fT);
    gemm_k<768, 96><<<dim3(12, 32), 64, 0, stream>>>(fT, W2, A2);
    reduce_bias_k<32><<<96, 256, 0, stream>>>(A2, b2, baseT, 24576);

    // 3) MetaNet coefficients
    metanet_k<<<32, 256, 0, stream>>>(baseT, mW1, mb1, mW2, mb2, coefs);

    // 4) scaled A-operands + delta-bias inits
    build_all_k<<<5184, 256, 0, stream>>>(coefs, xbarT, f0T, fT, dbp, db1, db2,
                                          G0T, G1T, G2T, df0b, dzb, doutb);

    // 5) JVP chain
    gemm_k<768, 128><<<dim3(12, 48), 64, 0, stream>>>(G0T, dWp, A3);          // 18.9 MB
    reduce_arr_k<48><<<96, 256, 0, stream>>>(A3, df0b, df0T, 24576);
    gemm_k<3072, 96><<<dim3(48, 8), 64, 0, stream>>>(df0T, W1, A1);           // slices 0..8
    gemm_k<3072, 256><<<dim3(48, 24), 64, 0, stream>>>(G1T, dW1, A1 + (size_t)8*98304); // 75.5 MB, 8..32
    reduce_mask_k<32><<<384, 256, 0, stream>>>(A1, dzb, zT, dfT);
    gemm_k<768, 96><<<dim3(12, 32), 64, 0, stream>>>(dfT, W2, A2);            // slices 0..32
    gemm_k<768, 256><<<dim3(12, 96), 64, 0, stream>>>(G2T, dW2, A2 + (size_t)32*24576); // 75.5 MB, 32..128
    reduce_out_k<128><<<96, 256, 0, stream>>>(A2, doutb, baseT, out);
}